// Round 13
// baseline (793.389 us; speedup 1.0000x reference)
//
#include <hip/hip_runtime.h>
#include <hip/hip_bf16.h>

typedef unsigned short u16;
typedef unsigned int u32;
typedef __attribute__((ext_vector_type(8))) __bf16 bf16x8;
typedef __attribute__((ext_vector_type(8))) unsigned short u16x8;
typedef __attribute__((ext_vector_type(4))) float floatx4;
typedef __attribute__((ext_vector_type(16))) float floatx16;

#define AS1 __attribute__((address_space(1)))
#define AS3 __attribute__((address_space(3)))

__device__ __forceinline__ u16 f2bf(float f) {
  unsigned u = __float_as_uint(f);
  u += 0x7fffu + ((u >> 16) & 1u);   // round-to-nearest-even (inputs finite)
  return (u16)(u >> 16);
}

__device__ __forceinline__ void g2lds16(const u16* g, u16* l) {
  __builtin_amdgcn_global_load_lds((AS1 void*)g, (AS3 void*)l, 16, 0, 0);
}

// ================= merged weight-prep kernel (x-cvt removed: GEMM1 reads x direct) =================
__device__ __forceinline__ void tcvt_body(const float* __restrict__ s,
                                          u16* __restrict__ d, int R, int C,
                                          int bx, int by, int tid,
                                          float (*t)[33]) {
  const int lx = tid & 31, ly = tid >> 5;
  const int x0 = bx * 32, y0 = by * 32;
  #pragma unroll
  for (int i = 0; i < 32; i += 8)
    t[ly + i][lx] = s[(size_t)(y0 + ly + i) * C + x0 + lx];
  __syncthreads();
  #pragma unroll
  for (int i = 0; i < 32; i += 8)
    d[(size_t)(x0 + ly + i) * R + y0 + lx] = f2bf(t[lx][ly + i]);
}

__global__ __launch_bounds__(256) void k_prep(
    const float* __restrict__ Wk, const float* __restrict__ Wv, u16* __restrict__ Wkv,
    const float* __restrict__ Wq, u16* __restrict__ WAt,
    const float* __restrict__ Wdn, u16* __restrict__ Wdt,
    const float* __restrict__ Wuk, u16* __restrict__ WBt,
    const float* __restrict__ Wuv, u16* __restrict__ WBt2,
    const float* __restrict__ Wo, u16* __restrict__ Wot) {
  __shared__ float t[32][33];
  const int b = blockIdx.x;
  const int tid = threadIdx.x;
  if (b < 512) {                        // Wk+Wv, n = 1048576
    long i = ((long)b * 256 + tid) * 8;
    float4 a0 = *(const float4*)(Wk + i);
    float4 a1 = *(const float4*)(Wk + i + 4);
    float4 b0 = *(const float4*)(Wv + i);
    float4 b1 = *(const float4*)(Wv + i + 4);
    u16x8 o;
    o[0] = f2bf(a0.x + b0.x); o[1] = f2bf(a0.y + b0.y);
    o[2] = f2bf(a0.z + b0.z); o[3] = f2bf(a0.w + b0.w);
    o[4] = f2bf(a1.x + b1.x); o[5] = f2bf(a1.y + b1.y);
    o[6] = f2bf(a1.z + b1.z); o[7] = f2bf(a1.w + b1.w);
    *(u16x8*)(Wkv + i) = o;
  } else if (b < 1536) {                // W_q^T
    int lb = b - 512;
    tcvt_body(Wq, WAt, 1024, 1024, lb & 31, lb >> 5, tid, t);
  } else if (b < 1792) {                // W_dn^T
    int lb = b - 1536;
    tcvt_body(Wdn, Wdt, 1024, 256, lb & 7, lb >> 3, tid, t);
  } else if (b < 2048) {                // W_uk^T -> WBt rows 0..1023
    int lb = b - 1792;
    tcvt_body(Wuk, WBt, 256, 1024, lb & 31, lb >> 5, tid, t);
  } else if (b < 2304) {                // W_uv^T -> WBt rows 1024..2047
    int lb = b - 2048;
    tcvt_body(Wuv, WBt2, 256, 1024, lb & 31, lb >> 5, tid, t);
  } else {                              // W_o^T
    int lb = b - 2304;
    tcvt_body(Wo, Wot, 1024, 1024, lb & 31, lb >> 5, tid, t);
  }
}

// ============ 128x128 4-wave bf16 GEMM (round-4 proven: 16x16x32 + T2 + T1) ============
// AF32=1: A is fp32 (x itself) — reg-staged (float4 x2 -> f2bf -> ds_write_b128)
// into the IDENTICAL swizzled LDS layout; inner loop & B path unchanged.
#define MFMA16(a, b, c) c = __builtin_amdgcn_mfma_f32_16x16x32_bf16(a, b, c, 0, 0, 0)
#define MFMA32(a, b, c) c = __builtin_amdgcn_mfma_f32_32x32x16_bf16(a, b, c, 0, 0, 0)

template <int MODE, int AF32>
__global__ __launch_bounds__(256, 3) void gemm128(
    const u16* __restrict__ A, const float* __restrict__ Af,
    const u16* __restrict__ Bt,
    int M, int N, int K, int ntn,
    u16* __restrict__ Cb, float* __restrict__ Cf,
    const float* __restrict__ memp, float* __restrict__ latf, u16* __restrict__ latb) {
  __shared__ u16 As[128 * 64];
  __shared__ u16 Bs[128 * 64];
  const int tid = threadIdx.x;
  const int lane = tid & 63;
  const int wid = tid >> 6;          // 4 waves: 2x2
  const int wr = wid >> 1, wc = wid & 1;

  // bijective XCD-aware swizzle (m204)
  int bid = blockIdx.x;
  {
    const int nwg = gridDim.x;
    const int q = nwg >> 3, r = nwg & 7;
    const int xcd = bid & 7, idx = bid >> 3;
    bid = (xcd < r ? xcd * (q + 1) : r * (q + 1) + (xcd - r) * q) + idx;
  }
  const int mt = bid / ntn, nt = bid % ntn;
  const int m0 = mt * 128, n0 = nt * 128;

  const int fr = lane & 15;
  const int g8 = (lane >> 4) * 8;
  const int xr = (lane & 7) * 8;     // read-side XOR (u16 units); row&7 == lane&7

  floatx4 acc[4][4];
  #pragma unroll
  for (int i = 0; i < 4; i++)
    #pragma unroll
    for (int j = 0; j < 4; j++) acc[i][j] = 0.0f;

  const u16* Ag0 = A + (size_t)m0 * K;
  const float* Afg0 = Af + (size_t)m0 * K;
  const u16* Bg0 = Bt + (size_t)n0 * K;

  for (int kt = 0; kt < K; kt += 64) {
    // B staging via DMA first (overlaps A's register loads below)
    #pragma unroll
    for (int p = 0; p < 4; p++) {
      int ci = p * 256 + tid;
      int row = ci >> 3;
      int kc = ((ci & 7) ^ (row & 7)) * 8;
      g2lds16(Bg0 + (size_t)row * K + kt + kc, &Bs[ci * 8]);
    }
    if (AF32) {
      // A reg-staged from fp32 source; same swizzled destination layout
      #pragma unroll
      for (int p = 0; p < 4; p++) {
        int ci = p * 256 + tid;
        int row = ci >> 3;
        int kc = ((ci & 7) ^ (row & 7)) * 8;
        const float* src = Afg0 + (size_t)row * K + kt + kc;
        float4 v0 = *(const float4*)src;
        float4 v1 = *(const float4*)(src + 4);
        u16x8 o;
        o[0] = f2bf(v0.x); o[1] = f2bf(v0.y); o[2] = f2bf(v0.z); o[3] = f2bf(v0.w);
        o[4] = f2bf(v1.x); o[5] = f2bf(v1.y); o[6] = f2bf(v1.z); o[7] = f2bf(v1.w);
        *(u16x8*)&As[ci * 8] = o;
      }
    } else {
      #pragma unroll
      for (int p = 0; p < 4; p++) {
        int ci = p * 256 + tid;
        int row = ci >> 3;
        int kc = ((ci & 7) ^ (row & 7)) * 8;
        g2lds16(Ag0 + (size_t)row * K + kt + kc, &As[ci * 8]);
      }
    }
    __syncthreads();
    #pragma unroll
    for (int kk = 0; kk < 64; kk += 32) {
      const int koff = kk + g8;
      bf16x8 af[4], bfv[4];
      #pragma unroll
      for (int i = 0; i < 4; i++)
        af[i] = *(const bf16x8*)&As[(wr * 64 + i * 16 + fr) * 64 + (koff ^ xr)];
      #pragma unroll
      for (int j = 0; j < 4; j++)
        bfv[j] = *(const bf16x8*)&Bs[(wc * 64 + j * 16 + fr) * 64 + (koff ^ xr)];
      #pragma unroll
      for (int i = 0; i < 4; i++)
        #pragma unroll
        for (int j = 0; j < 4; j++)
          MFMA16(af[i], bfv[j], acc[i][j]);
    }
    __syncthreads();
  }

  #pragma unroll
  for (int i = 0; i < 4; i++) {
    const int mb = m0 + wr * 64 + i * 16 + ((lane >> 4) * 4);
    #pragma unroll
    for (int j = 0; j < 4; j++) {
      const int cb = n0 + wc * 64 + j * 16 + (lane & 15);
      #pragma unroll
      for (int r = 0; r < 4; r++) {
        const int m = mb + r;
        const float v = acc[i][j][r];
        if (MODE == 0) {
          Cb[(size_t)m * N + cb] = f2bf(v);
        } else if (MODE == 1) {
          if (n0 < 1024) {
            Cb[(size_t)m * 1024 + cb] = f2bf(v);   // q, ld=1024
          } else {
            int lc = cb - 1024;                     // latent col 0..255
            float lv = (v + memp[(size_t)m * 256 + lc]) * 0.5f;
            latf[(size_t)m * 256 + lc] = lv;        // fp32 output #2
            latb[(size_t)m * 256 + lc] = f2bf(lv);  // bf16 for attention
          }
        } else {
          Cf[(size_t)m * N + cb] = v;
        }
      }
    }
  }
}

// ---------------- attention (round-4 proven): per block = 4 heads of one batch ----------------
__global__ __launch_bounds__(256) void k_attn(const u16* __restrict__ KV, u16* Q) {
  __shared__ u16 Qs[4][32][72];   // reused as P (32x40) per wave after QK^T
  __shared__ u16 Ks[4][32][72];
  __shared__ u16 Vt[4][64][40];   // v transposed: [head][d][key]
  const int tid = threadIdx.x;
  const int hg = blockIdx.x;      // head group 0..3
  const int b = blockIdx.y;       // batch 0..2047
  const long tok0 = (long)b * 32;

  {
    const int t = tid >> 3, ci = tid & 7;
    const int hd = ci >> 1, c0 = (ci & 1) * 32;
    const u16* qrow = Q + (tok0 + t) * 1024 + hg * 256 + ci * 32;
    #pragma unroll
    for (int u = 0; u < 4; u++)
      *(u16x8*)&Qs[hd][t][c0 + u * 8] = *(const u16x8*)(qrow + u * 8);
    const u16* krow = KV + (tok0 + t) * 2048 + hg * 256 + ci * 32;
    #pragma unroll
    for (int u = 0; u < 4; u++)
      *(u16x8*)&Ks[hd][t][c0 + u * 8] = *(const u16x8*)(krow + u * 8);
    const u16* vrow = KV + (tok0 + t) * 2048 + 1024 + hg * 256 + ci * 32;
    #pragma unroll
    for (int u = 0; u < 4; u++) {
      u16x8 v = *(const u16x8*)(vrow + u * 8);
      #pragma unroll
      for (int j = 0; j < 8; j++) Vt[hd][c0 + u * 8 + j][t] = v[j];
    }
  }
  __syncthreads();

  const int w = tid >> 6;
  const int lane = tid & 63;
  const int col = lane & 31, hi = lane >> 5;

  floatx16 S;
  #pragma unroll
  for (int r = 0; r < 16; r++) S[r] = 0.0f;
  #pragma unroll
  for (int kc = 0; kc < 4; kc++) {
    bf16x8 aq = *(const bf16x8*)&Qs[w][col][kc * 16 + hi * 8];
    bf16x8 bk = *(const bf16x8*)&Ks[w][col][kc * 16 + hi * 8];
    MFMA32(aq, bk, S);
  }

  u16* Pw = &Qs[w][0][0];
  float pr[16];
  #pragma unroll
  for (int r = 0; r < 16; r++) {
    float sc = S[r] * 0.03125f;    // 1/sqrt(1024)
    float mx = sc;
    #pragma unroll
    for (int off = 16; off >= 1; off >>= 1) mx = fmaxf(mx, __shfl_xor(mx, off, 64));
    float e = __expf(sc - mx);
    float sm = e;
    #pragma unroll
    for (int off = 16; off >= 1; off >>= 1) sm += __shfl_xor(sm, off, 64);
    pr[r] = e / sm;
  }
  #pragma unroll
  for (int r = 0; r < 16; r++) {
    int row = (r & 3) + 8 * (r >> 2) + 4 * hi;
    Pw[row * 40 + col] = f2bf(pr[r]);
  }
  __syncthreads();

  floatx16 c0v, c1v;
  #pragma unroll
  for (int r = 0; r < 16; r++) { c0v[r] = 0.0f; c1v[r] = 0.0f; }
  #pragma unroll
  for (int kc = 0; kc < 2; kc++) {
    bf16x8 ap = *(const bf16x8*)&Pw[col * 40 + kc * 16 + hi * 8];
    bf16x8 bv0 = *(const bf16x8*)&Vt[w][col][kc * 16 + hi * 8];
    bf16x8 bv1 = *(const bf16x8*)&Vt[w][32 + col][kc * 16 + hi * 8];
    MFMA32(ap, bv0, c0v);
    MFMA32(ap, bv1, c1v);
  }
  #pragma unroll
  for (int r = 0; r < 16; r++) {
    int row = (r & 3) + 8 * (r >> 2) + 4 * hi;
    u16* orow = Q + (tok0 + row) * 1024 + hg * 256 + w * 64;
    orow[col] = f2bf(c0v[r]);
    orow[col + 32] = f2bf(c1v[r]);
  }
}

extern "C" void kernel_launch(void* const* d_in, const int* in_sizes, int n_in,
                              void* d_out, int out_size, void* d_ws, size_t ws_size,
                              hipStream_t stream) {
  const float* x    = (const float*)d_in[0];
  const float* mem  = (const float*)d_in[1];
  const float* W_q  = (const float*)d_in[2];
  const float* W_k  = (const float*)d_in[3];
  const float* W_v  = (const float*)d_in[4];
  const float* W_o  = (const float*)d_in[5];
  const float* W_dn = (const float*)d_in[6];
  const float* W_uk = (const float*)d_in[7];
  const float* W_uv = (const float*)d_in[8];
  float* out  = (float*)d_out;
  float* latf = out + (size_t)67108864;   // latent_kv fp32 output

  char* wp = (char*)d_ws;
  u16* Qb  = (u16*)wp; wp += (size_t)65536 * 1024 * 2;  // q / ctx bf16
  u16* Lb  = (u16*)wp; wp += (size_t)65536 * 256 * 2;   // latent bf16
  u16* WAt = (u16*)wp; wp += (size_t)1280 * 1024 * 2;   // [W_q | W_kvd]^T
  u16* WBt = (u16*)wp; wp += (size_t)2048 * 256 * 2;    // [W_up_k | W_up_v]^T
  u16* Wot = (u16*)wp; wp += (size_t)1024 * 1024 * 2;   // W_o^T
  u16* Wdt = (u16*)wp; wp += (size_t)256 * 1024 * 2;    // W_down^T
  u16* Wkv = (u16*)wp; wp += (size_t)1024 * 1024 * 2;   // (Wk+Wv) bf16

  u16* KVb = (u16*)d_out;  // kv_rec bf16 (aliased into out region; dead before GEMM3)

  dim3 b256(256);

  // merged weight-prep (x no longer pre-converted)
  k_prep<<<3328, b256, 0, stream>>>(
      W_k, W_v, Wkv, W_q, WAt, W_dn, Wdt,
      W_uk, WBt, W_uv, WBt + (size_t)1024 * 256, W_o, Wot);

  // W_kvd^T = Wdt @ Wkv^T -> WAt rows 1024..1279  (M=256, N=1024, 16 blocks)
  gemm128<0, 0><<<16, b256, 0, stream>>>(
      Wdt, nullptr, Wkv, 256, 1024, 1024, 8, WAt + (size_t)1024 * 1024,
      nullptr, nullptr, nullptr, nullptr);

  // GEMM1: [q | latent_pre] = x @ [W_q | W_kvd]   (512 x 10 tiles, A = fp32 x direct)
  gemm128<1, 1><<<5120, b256, 0, stream>>>(
      nullptr, x, WAt, 65536, 1280, 1024, 10, Qb, nullptr, mem, latf, Lb);

  // GEMM2: [k_rec | v_rec] = latent @ [W_up_k | W_up_v]   (512 x 16 tiles)
  gemm128<0, 0><<<8192, b256, 0, stream>>>(
      Lb, nullptr, WBt, 65536, 2048, 256, 16, KVb, nullptr, nullptr, nullptr, nullptr);

  // attention (ctx overwrites Qb in place)
  k_attn<<<dim3(4, 2048), b256, 0, stream>>>(KVb, Qb);

  // GEMM3: out = ctx @ W_o (fp32)   (512 x 8 tiles)
  gemm128<2, 0><<<4096, b256, 0, stream>>>(
      Qb, nullptr, Wot, 65536, 1024, 1024, 8, nullptr, out, nullptr, nullptr, nullptr);
}

// Round 14
// 783.508 us; speedup vs baseline: 1.0126x; 1.0126x over previous
//
#include <hip/hip_runtime.h>
#include <hip/hip_bf16.h>

typedef unsigned short u16;
typedef unsigned int u32;
typedef __attribute__((ext_vector_type(8))) __bf16 bf16x8;
typedef __attribute__((ext_vector_type(8))) unsigned short u16x8;
typedef __attribute__((ext_vector_type(4))) float floatx4;
typedef __attribute__((ext_vector_type(16))) float floatx16;

#define AS1 __attribute__((address_space(1)))
#define AS3 __attribute__((address_space(3)))

__device__ __forceinline__ u16 f2bf(float f) {
  unsigned u = __float_as_uint(f);
  u += 0x7fffu + ((u >> 16) & 1u);   // round-to-nearest-even (inputs finite)
  return (u16)(u >> 16);
}

__device__ __forceinline__ void g2lds16(const u16* g, u16* l) {
  __builtin_amdgcn_global_load_lds((AS1 void*)g, (AS3 void*)l, 16, 0, 0);
}

// ================= merged prep kernel (proven rounds 9/11) =================
__device__ __forceinline__ void tcvt_body(const float* __restrict__ s,
                                          u16* __restrict__ d, int R, int C,
                                          int bx, int by, int tid,
                                          float (*t)[33]) {
  const int lx = tid & 31, ly = tid >> 5;
  const int x0 = bx * 32, y0 = by * 32;
  #pragma unroll
  for (int i = 0; i < 32; i += 8)
    t[ly + i][lx] = s[(size_t)(y0 + ly + i) * C + x0 + lx];
  __syncthreads();
  #pragma unroll
  for (int i = 0; i < 32; i += 8)
    d[(size_t)(x0 + ly + i) * R + y0 + lx] = f2bf(t[lx][ly + i]);
}

__global__ __launch_bounds__(256) void k_prep(
    const float* __restrict__ x, u16* __restrict__ Xb,
    const float* __restrict__ Wk, const float* __restrict__ Wv, u16* __restrict__ Wkv,
    const float* __restrict__ Wq, u16* __restrict__ WAt,
    const float* __restrict__ Wdn, u16* __restrict__ Wdt,
    const float* __restrict__ Wuk, u16* __restrict__ WBt,
    const float* __restrict__ Wuv, u16* __restrict__ WBt2,
    const float* __restrict__ Wo, u16* __restrict__ Wot) {
  __shared__ float t[32][33];
  const int b = blockIdx.x;
  const int tid = threadIdx.x;
  if (b < 4096) {                       // x convert, n = 67108864
    long i = ((long)b * 256 + tid) * 8;
    const long stride = (long)4096 * 256 * 8;
    for (; i < 67108864L; i += stride) {
      float4 a = *(const float4*)(x + i);
      float4 c = *(const float4*)(x + i + 4);
      u16x8 o;
      o[0] = f2bf(a.x); o[1] = f2bf(a.y); o[2] = f2bf(a.z); o[3] = f2bf(a.w);
      o[4] = f2bf(c.x); o[5] = f2bf(c.y); o[6] = f2bf(c.z); o[7] = f2bf(c.w);
      *(u16x8*)(Xb + i) = o;
    }
  } else if (b < 4608) {                // Wk+Wv, n = 1048576
    long i = ((long)(b - 4096) * 256 + tid) * 8;
    float4 a0 = *(const float4*)(Wk + i);
    float4 a1 = *(const float4*)(Wk + i + 4);
    float4 b0 = *(const float4*)(Wv + i);
    float4 b1 = *(const float4*)(Wv + i + 4);
    u16x8 o;
    o[0] = f2bf(a0.x + b0.x); o[1] = f2bf(a0.y + b0.y);
    o[2] = f2bf(a0.z + b0.z); o[3] = f2bf(a0.w + b0.w);
    o[4] = f2bf(a1.x + b1.x); o[5] = f2bf(a1.y + b1.y);
    o[6] = f2bf(a1.z + b1.z); o[7] = f2bf(a1.w + b1.w);
    *(u16x8*)(Wkv + i) = o;
  } else if (b < 5632) {                // W_q^T
    int lb = b - 4608;
    tcvt_body(Wq, WAt, 1024, 1024, lb & 31, lb >> 5, tid, t);
  } else if (b < 5888) {                // W_dn^T
    int lb = b - 5632;
    tcvt_body(Wdn, Wdt, 1024, 256, lb & 7, lb >> 3, tid, t);
  } else if (b < 6144) {                // W_uk^T -> WBt rows 0..1023
    int lb = b - 5888;
    tcvt_body(Wuk, WBt, 256, 1024, lb & 31, lb >> 5, tid, t);
  } else if (b < 6400) {                // W_uv^T -> WBt rows 1024..2047
    int lb = b - 6144;
    tcvt_body(Wuv, WBt2, 256, 1024, lb & 31, lb >> 5, tid, t);
  } else {                              // W_o^T
    int lb = b - 6400;
    tcvt_body(Wo, Wot, 1024, 1024, lb & 31, lb >> 5, tid, t);
  }
}

// ============ 128x128 4-wave bf16 GEMM (round-4 proven: 16x16x32 + T2 + T1) ============
#define MFMA16(a, b, c) c = __builtin_amdgcn_mfma_f32_16x16x32_bf16(a, b, c, 0, 0, 0)
#define MFMA32(a, b, c) c = __builtin_amdgcn_mfma_f32_32x32x16_bf16(a, b, c, 0, 0, 0)

template <int MODE>
__global__ __launch_bounds__(256, 3) void gemm128(
    const u16* __restrict__ A, const u16* __restrict__ Bt,
    int M, int N, int K, int ntn,
    u16* __restrict__ Cb, float* __restrict__ Cf,
    const float* __restrict__ memp, float* __restrict__ latf, u16* __restrict__ latb) {
  __shared__ u16 As[128 * 64];
  __shared__ u16 Bs[128 * 64];
  const int tid = threadIdx.x;
  const int lane = tid & 63;
  const int wid = tid >> 6;          // 4 waves: 2x2
  const int wr = wid >> 1, wc = wid & 1;

  // bijective XCD-aware swizzle (m204)
  int bid = blockIdx.x;
  {
    const int nwg = gridDim.x;
    const int q = nwg >> 3, r = nwg & 7;
    const int xcd = bid & 7, idx = bid >> 3;
    bid = (xcd < r ? xcd * (q + 1) : r * (q + 1) + (xcd - r) * q) + idx;
  }
  const int mt = bid / ntn, nt = bid % ntn;
  const int m0 = mt * 128, n0 = nt * 128;

  const int fr = lane & 15;
  const int g8 = (lane >> 4) * 8;
  const int xr = (lane & 7) * 8;     // read-side XOR (u16 units); row&7 == lane&7

  floatx4 acc[4][4];
  #pragma unroll
  for (int i = 0; i < 4; i++)
    #pragma unroll
    for (int j = 0; j < 4; j++) acc[i][j] = 0.0f;

  const u16* Ag0 = A + (size_t)m0 * K;
  const u16* Bg0 = Bt + (size_t)n0 * K;

  for (int kt = 0; kt < K; kt += 64) {
    #pragma unroll
    for (int p = 0; p < 4; p++) {
      int ci = p * 256 + tid;
      int row = ci >> 3;
      int kc = ((ci & 7) ^ (row & 7)) * 8;   // pre-swizzled source col
      g2lds16(Ag0 + (size_t)row * K + kt + kc, &As[ci * 8]);
    }
    #pragma unroll
    for (int p = 0; p < 4; p++) {
      int ci = p * 256 + tid;
      int row = ci >> 3;
      int kc = ((ci & 7) ^ (row & 7)) * 8;
      g2lds16(Bg0 + (size_t)row * K + kt + kc, &Bs[ci * 8]);
    }
    __syncthreads();
    #pragma unroll
    for (int kk = 0; kk < 64; kk += 32) {
      const int koff = kk + g8;
      bf16x8 af[4], bfv[4];
      #pragma unroll
      for (int i = 0; i < 4; i++)
        af[i] = *(const bf16x8*)&As[(wr * 64 + i * 16 + fr) * 64 + (koff ^ xr)];
      #pragma unroll
      for (int j = 0; j < 4; j++)
        bfv[j] = *(const bf16x8*)&Bs[(wc * 64 + j * 16 + fr) * 64 + (koff ^ xr)];
      #pragma unroll
      for (int i = 0; i < 4; i++)
        #pragma unroll
        for (int j = 0; j < 4; j++)
          MFMA16(af[i], bfv[j], acc[i][j]);
    }
    __syncthreads();
  }

  #pragma unroll
  for (int i = 0; i < 4; i++) {
    const int mb = m0 + wr * 64 + i * 16 + ((lane >> 4) * 4);
    #pragma unroll
    for (int j = 0; j < 4; j++) {
      const int cb = n0 + wc * 64 + j * 16 + (lane & 15);
      #pragma unroll
      for (int r = 0; r < 4; r++) {
        const int m = mb + r;
        const float v = acc[i][j][r];
        if (MODE == 0) {
          Cb[(size_t)m * N + cb] = f2bf(v);
        } else if (MODE == 1) {
          if (n0 < 1024) {
            Cb[(size_t)m * 1024 + cb] = f2bf(v);   // q, ld=1024
          } else {
            int lc = cb - 1024;                     // latent col 0..255
            float lv = (v + memp[(size_t)m * 256 + lc]) * 0.5f;
            latf[(size_t)m * 256 + lc] = lv;        // fp32 output #2
            latb[(size_t)m * 256 + lc] = f2bf(lv);  // bf16 for attention
          }
        } else {
          Cf[(size_t)m * N + cb] = v;
        }
      }
    }
  }
}

// ---------------- attention (round-4 proven): per block = 4 heads of one batch ----------------
__global__ __launch_bounds__(256) void k_attn(const u16* __restrict__ KV, u16* Q) {
  __shared__ u16 Qs[4][32][72];   // reused as P (32x40) per wave after QK^T
  __shared__ u16 Ks[4][32][72];
  __shared__ u16 Vt[4][64][40];   // v transposed: [head][d][key]
  const int tid = threadIdx.x;
  const int hg = blockIdx.x;      // head group 0..3
  const int b = blockIdx.y;       // batch 0..2047
  const long tok0 = (long)b * 32;

  {
    const int t = tid >> 3, ci = tid & 7;
    const int hd = ci >> 1, c0 = (ci & 1) * 32;
    const u16* qrow = Q + (tok0 + t) * 1024 + hg * 256 + ci * 32;
    #pragma unroll
    for (int u = 0; u < 4; u++)
      *(u16x8*)&Qs[hd][t][c0 + u * 8] = *(const u16x8*)(qrow + u * 8);
    const u16* krow = KV + (tok0 + t) * 2048 + hg * 256 + ci * 32;
    #pragma unroll
    for (int u = 0; u < 4; u++)
      *(u16x8*)&Ks[hd][t][c0 + u * 8] = *(const u16x8*)(krow + u * 8);
    const u16* vrow = KV + (tok0 + t) * 2048 + 1024 + hg * 256 + ci * 32;
    #pragma unroll
    for (int u = 0; u < 4; u++) {
      u16x8 v = *(const u16x8*)(vrow + u * 8);
      #pragma unroll
      for (int j = 0; j < 8; j++) Vt[hd][c0 + u * 8 + j][t] = v[j];
    }
  }
  __syncthreads();

  const int w = tid >> 6;
  const int lane = tid & 63;
  const int col = lane & 31, hi = lane >> 5;

  floatx16 S;
  #pragma unroll
  for (int r = 0; r < 16; r++) S[r] = 0.0f;
  #pragma unroll
  for (int kc = 0; kc < 4; kc++) {
    bf16x8 aq = *(const bf16x8*)&Qs[w][col][kc * 16 + hi * 8];
    bf16x8 bk = *(const bf16x8*)&Ks[w][col][kc * 16 + hi * 8];
    MFMA32(aq, bk, S);
  }

  u16* Pw = &Qs[w][0][0];
  float pr[16];
  #pragma unroll
  for (int r = 0; r < 16; r++) {
    float sc = S[r] * 0.03125f;    // 1/sqrt(1024)
    float mx = sc;
    #pragma unroll
    for (int off = 16; off >= 1; off >>= 1) mx = fmaxf(mx, __shfl_xor(mx, off, 64));
    float e = __expf(sc - mx);
    float sm = e;
    #pragma unroll
    for (int off = 16; off >= 1; off >>= 1) sm += __shfl_xor(sm, off, 64);
    pr[r] = e / sm;
  }
  #pragma unroll
  for (int r = 0; r < 16; r++) {
    int row = (r & 3) + 8 * (r >> 2) + 4 * hi;
    Pw[row * 40 + col] = f2bf(pr[r]);
  }
  __syncthreads();

  floatx16 c0v, c1v;
  #pragma unroll
  for (int r = 0; r < 16; r++) { c0v[r] = 0.0f; c1v[r] = 0.0f; }
  #pragma unroll
  for (int kc = 0; kc < 2; kc++) {
    bf16x8 ap = *(const bf16x8*)&Pw[col * 40 + kc * 16 + hi * 8];
    bf16x8 bv0 = *(const bf16x8*)&Vt[w][col][kc * 16 + hi * 8];
    bf16x8 bv1 = *(const bf16x8*)&Vt[w][32 + col][kc * 16 + hi * 8];
    MFMA32(ap, bv0, c0v);
    MFMA32(ap, bv1, c1v);
  }
  #pragma unroll
  for (int r = 0; r < 16; r++) {
    int row = (r & 3) + 8 * (r >> 2) + 4 * hi;
    u16* orow = Q + (tok0 + row) * 1024 + hg * 256 + w * 64;
    orow[col] = f2bf(c0v[r]);
    orow[col + 32] = f2bf(c1v[r]);
  }
}

extern "C" void kernel_launch(void* const* d_in, const int* in_sizes, int n_in,
                              void* d_out, int out_size, void* d_ws, size_t ws_size,
                              hipStream_t stream) {
  const float* x    = (const float*)d_in[0];
  const float* mem  = (const float*)d_in[1];
  const float* W_q  = (const float*)d_in[2];
  const float* W_k  = (const float*)d_in[3];
  const float* W_v  = (const float*)d_in[4];
  const float* W_o  = (const float*)d_in[5];
  const float* W_dn = (const float*)d_in[6];
  const float* W_uk = (const float*)d_in[7];
  const float* W_uv = (const float*)d_in[8];
  float* out  = (float*)d_out;
  float* latf = out + (size_t)67108864;   // latent_kv fp32 output

  char* wp = (char*)d_ws;
  u16* Qb  = (u16*)wp; wp += (size_t)65536 * 1024 * 2;  // q / ctx bf16
  u16* Lb  = (u16*)wp; wp += (size_t)65536 * 256 * 2;   // latent bf16
  u16* WAt = (u16*)wp; wp += (size_t)1280 * 1024 * 2;   // [W_q | W_kvd]^T
  u16* WBt = (u16*)wp; wp += (size_t)2048 * 256 * 2;    // [W_up_k | W_up_v]^T
  u16* Wot = (u16*)wp; wp += (size_t)1024 * 1024 * 2;   // W_o^T
  u16* Wdt = (u16*)wp; wp += (size_t)256 * 1024 * 2;    // W_down^T
  u16* Wkv = (u16*)wp; wp += (size_t)1024 * 1024 * 2;   // (Wk+Wv) bf16

  u16* Xb  = (u16*)d_out;  // x bf16 (aliased; dead after GEMM1)
  u16* KVb = (u16*)d_out;  // kv_rec bf16 (overwrites Xb after GEMM1)

  dim3 b256(256);

  // one merged prep kernel (x cvt + all weight prep)
  k_prep<<<7424, b256, 0, stream>>>(
      x, Xb, W_k, W_v, Wkv, W_q, WAt, W_dn, Wdt,
      W_uk, WBt, W_uv, WBt + (size_t)1024 * 256, W_o, Wot);

  // W_kvd^T = Wdt @ Wkv^T -> WAt rows 1024..1279  (M=256, N=1024, 16 blocks)
  gemm128<0><<<16, b256, 0, stream>>>(
      Wdt, Wkv, 256, 1024, 1024, 8, WAt + (size_t)1024 * 1024,
      nullptr, nullptr, nullptr, nullptr);

  // GEMM1: [q | latent_pre] = x @ [W_q | W_kvd]   (512 x 10 tiles)
  gemm128<1><<<5120, b256, 0, stream>>>(
      Xb, WAt, 65536, 1280, 1024, 10, Qb, nullptr, mem, latf, Lb);

  // GEMM2: [k_rec | v_rec] = latent @ [W_up_k | W_up_v]   (512 x 16 tiles)
  gemm128<0><<<8192, b256, 0, stream>>>(
      Lb, WBt, 65536, 2048, 256, 16, KVb, nullptr, nullptr, nullptr, nullptr);

  // attention (ctx overwrites Qb in place)
  k_attn<<<dim3(4, 2048), b256, 0, stream>>>(KVb, Qb);

  // GEMM3: out = ctx @ W_o (fp32)   (512 x 8 tiles)
  gemm128<2><<<4096, b256, 0, stream>>>(
      Qb, Wot, 65536, 1024, 1024, 8, nullptr, out, nullptr, nullptr, nullptr);
}